// Round 2
// baseline (265.779 us; speedup 1.0000x reference)
//
#include <hip/hip_runtime.h>

#define B_ 8
#define C_ 256
#define I_ 128
#define N_ 4096
#define BN_ (B_ * N_)
#define LOG2E 1.4426950408889634f

typedef __attribute__((ext_vector_type(8))) short bf16x8;
typedef __attribute__((ext_vector_type(4))) float f32x4;
typedef __attribute__((ext_vector_type(4))) int i32x4;

static __device__ __forceinline__ short f2bf(float f) {
    unsigned u = __float_as_uint(f);
    unsigned r = u + 0x7fffu + ((u >> 16) & 1u);  // RNE
    return (short)(r >> 16);
}
static __device__ __forceinline__ float bf2f(short s) {
    return __uint_as_float(((unsigned)(unsigned short)s) << 16);
}
static __device__ __forceinline__ unsigned cvt_pk_bf16(float lo, float hi) {
    unsigned r;
    asm("v_cvt_pk_bf16_f32 %0, %1, %2" : "=v"(r) : "v"(lo), "v"(hi));
    return r;
}

// ---------------- K0: weight prep (theta scaled by log2e) ----------------
__global__ void k_prep(const float* g_w, const float* theta_w, const float* phi_w,
                       const float* g_b, const float* theta_b, const float* phi_b,
                       const float* w_w, short* wcat, short* wwb, float* bcat) {
    int i = blockIdx.x * 256 + threadIdx.x;
    if (i < 384 * 256) {
        int j = i >> 8, c = i & 255;
        float v = (j < 128) ? theta_w[j * 256 + c] * LOG2E
                : (j < 256) ? phi_w[(j - 128) * 256 + c]
                            : g_w[(j - 256) * 256 + c];
        wcat[i] = f2bf(v);
    } else if (i < 384 * 256 + 256 * 128) {
        int k = i - 384 * 256;
        wwb[k] = f2bf(w_w[k]);
    } else if (i < 384 * 256 + 256 * 128 + 384) {
        int j = i - (384 * 256 + 256 * 128);
        bcat[j] = (j < 128) ? theta_b[j] * LOG2E
                : (j < 256) ? phi_b[j - 128] : g_b[j - 256];
    }
}

// ---------------- K1: projection (R2-exact) -> tp[B][N][256], gmat[B][I][N] ---
__global__ __launch_bounds__(256) void k_proj(const float* __restrict__ x,
                                              const short* __restrict__ wcat,
                                              const float* __restrict__ bcat,
                                              short* __restrict__ tp,
                                              short* __restrict__ gmat) {
    int b = blockIdx.y;
    int n0 = blockIdx.x * 64;
    int tid = threadIdx.x;
    int wave = tid >> 6, lane = tid & 63, s = lane & 15, q = lane >> 4;
    __shared__ short xs[64][264];  // [n-local][c]

#pragma unroll
    for (int it = 0; it < 16; ++it) {
        int cr = (tid >> 4) + it * 16;
        int nc = tid & 15;
        const float4 v = *(const float4*)&x[((size_t)b * C_ + cr) * N_ + n0 + nc * 4];
        xs[nc * 4 + 0][cr] = f2bf(v.x);
        xs[nc * 4 + 1][cr] = f2bf(v.y);
        xs[nc * 4 + 2][cr] = f2bf(v.z);
        xs[nc * 4 + 3][cr] = f2bf(v.w);
    }
    __syncthreads();

    f32x4 acc[4][6];
#pragma unroll
    for (int rt = 0; rt < 4; ++rt)
#pragma unroll
        for (int jt = 0; jt < 6; ++jt) acc[rt][jt] = (f32x4){0.f, 0.f, 0.f, 0.f};

#pragma unroll
    for (int kb = 0; kb < 8; ++kb) {
        bf16x8 af[4], bfv[6];
#pragma unroll
        for (int rt = 0; rt < 4; ++rt)
            af[rt] = *(const bf16x8*)&xs[rt * 16 + s][kb * 32 + q * 8];
#pragma unroll
        for (int jt = 0; jt < 6; ++jt)
            bfv[jt] = *(const bf16x8*)&wcat[(wave * 96 + jt * 16 + s) * 256 + kb * 32 + q * 8];
#pragma unroll
        for (int rt = 0; rt < 4; ++rt)
#pragma unroll
            for (int jt = 0; jt < 6; ++jt)
                acc[rt][jt] = __builtin_amdgcn_mfma_f32_16x16x32_bf16(af[rt], bfv[jt], acc[rt][jt], 0, 0, 0);
    }

#pragma unroll
    for (int rt = 0; rt < 4; ++rt)
#pragma unroll
        for (int jt = 0; jt < 6; ++jt) {
            int j = wave * 96 + jt * 16 + s;
            float bias = bcat[j];
#pragma unroll
            for (int r = 0; r < 4; ++r) {
                int n = n0 + rt * 16 + 4 * q + r;
                float v = acc[rt][jt][r] + bias;
                if (j < 256)
                    tp[((size_t)b * N_ + n) * 256 + j] = f2bf(v);
                else
                    gmat[((size_t)b * I_ + (j - 256)) * N_ + n] = f2bf(v);
            }
        }
}

// ---- K2: flash attention, Q-tile 128, split-K 2, no online max ---------------
// theta pre-scaled by log2e -> P = exp2(S). Unnormalized f32 Op + l sums.
// S computed TRANSPOSED (mfma(K,Q)). P never touches LDS: cvt_pk pairs are
// redistributed to the PV A-frag layout with 2x permlane32_swap + 2x
// permlane16_swap per (fr,kb2) (pairs [rA,rB,rC,rD] -> lane q gets 4q..4q+3).
// M-tile 128 (two 64-key sub-tiles per barrier window): half the barriers,
// two independent S->P->PV chains for ILP at the grid-fixed 2 waves/SIMD.
__global__ __launch_bounds__(256, 2) void k_attn(const short* __restrict__ tp,
                                                 const short* __restrict__ gmat,
                                                 float* __restrict__ Op,
                                                 float* __restrict__ lbuf) {
    int id = blockIdx.x;
    int b = id & 7;               // XCD swizzle: one batch's K/V per XCD L2
    int qt = (id >> 3) & 31;
    int half = id >> 8;
    int n0 = qt * 128;
    int tid = threadIdx.x;
    int wave = tid >> 6, lane = tid & 63, s = lane & 15, q = lane >> 4;

    __shared__ __align__(16) short Kt[128 * 128];  // phi [key m][i], swizzled, 32KB
    __shared__ __align__(16) short Vt[128 * 128];  // g   [i][key m], swizzled, 32KB

    char* KtB = (char*)Kt;
    char* VtB = (char*)Vt;

    const int swz = (s & 7) << 4;
    // S-phase K A-frag reads: addr(h,tc,kb) = kA[kb] + h*16384 + tc*4096
    int kA[4];
#pragma unroll
    for (int kb = 0; kb < 4; ++kb) kA[kb] = s * 256 + ((kb * 64 + q * 16) ^ swz);
    // PV V B-frag reads: addr(h,kb2,t) = vA[kb2] + h*128 + t*4096
    int vA[2];
#pragma unroll
    for (int kb2 = 0; kb2 < 2; ++kb2)
        vA[kb2] = s * 256 + ((kb2 * 64 + q * 16) ^ swz);
    // staging write base (same geometry for Kt and Vt: row stride 256B)
    int krow = tid >> 4, kch = tid & 15;
    int stW = krow * 256 + ((kch * 16) ^ ((krow & 7) << 4));

    // Q fragments (B-operand of S^T): rows n0 + wave*32 + fr*16 + s
    bf16x8 qf[2][4];
#pragma unroll
    for (int fr = 0; fr < 2; ++fr) {
        const short* qb = tp + ((size_t)b * N_ + n0 + wave * 32 + fr * 16 + s) * 256;
#pragma unroll
        for (int kb = 0; kb < 4; ++kb) qf[fr][kb] = *(const bf16x8*)(qb + kb * 32 + q * 8);
    }

    f32x4 ot[2][8];  // O: frag fr rows=query 4q+r, cols = i (t*16+s)
#pragma unroll
    for (int fr = 0; fr < 2; ++fr)
#pragma unroll
        for (int t = 0; t < 8; ++t) ot[fr][t] = (f32x4){0.f, 0.f, 0.f, 0.f};
    float lsum[2] = {0.f, 0.f};  // per-lane partial for query fr*16+s

    const int mStart = half * 2048, mEnd = mStart + 2048;

    bf16x8 pk[8], pv[8];
#pragma unroll
    for (int it = 0; it < 8; ++it) {
        pk[it] = *(const bf16x8*)&tp[((size_t)b * N_ + mStart + krow + it * 16) * 256 + 128 + kch * 8];
        pv[it] = *(const bf16x8*)&gmat[((size_t)b * I_ + krow + it * 16) * N_ + mStart + kch * 8];
    }

    for (int m0 = mStart; m0 < mEnd; m0 += 128) {
        __syncthreads();  // previous compute done; LDS free
#pragma unroll
        for (int it = 0; it < 8; ++it) {
            *(bf16x8*)(KtB + stW + it * 4096) = pk[it];
            *(bf16x8*)(VtB + stW + it * 4096) = pv[it];
        }
        __syncthreads();
        if (m0 + 128 < mEnd) {  // next-tile loads hide behind compute
#pragma unroll
            for (int it = 0; it < 8; ++it) {
                pk[it] = *(const bf16x8*)&tp[((size_t)b * N_ + m0 + 128 + krow + it * 16) * 256 + 128 + kch * 8];
                pv[it] = *(const bf16x8*)&gmat[((size_t)b * I_ + krow + it * 16) * N_ + m0 + 128 + kch * 8];
            }
        }

#pragma unroll
        for (int h = 0; h < 2; ++h) {   // two 64-key sub-tiles
            const int hK = h * 16384;   // 64 rows * 256B
            const int hV = h * 128;     // 64 key-cols * 2B

            // S^T = mfma(K, Q): D[row=key tc*16+4q+r][col=query s]
            f32x4 sa[2][4];
#pragma unroll
            for (int fr = 0; fr < 2; ++fr)
#pragma unroll
                for (int tc = 0; tc < 4; ++tc) sa[fr][tc] = (f32x4){0.f, 0.f, 0.f, 0.f};
            __builtin_amdgcn_s_setprio(1);
#pragma unroll
            for (int tc = 0; tc < 4; ++tc) {
                bf16x8 bfv[4];
#pragma unroll
                for (int kb = 0; kb < 4; ++kb)
                    bfv[kb] = *(const bf16x8*)(KtB + hK + kA[kb] + tc * 4096);
#pragma unroll
                for (int fr = 0; fr < 2; ++fr)
#pragma unroll
                    for (int kb = 0; kb < 4; ++kb)
                        sa[fr][tc] = __builtin_amdgcn_mfma_f32_16x16x32_bf16(bfv[kb], qf[fr][kb], sa[fr][tc], 0, 0, 0);
            }
            __builtin_amdgcn_s_setprio(0);

            // P = exp2(S), l accumulation, pack pairs (key 2p, 2p+1)
            unsigned W[2][4][2];
#pragma unroll
            for (int fr = 0; fr < 2; ++fr) {
#pragma unroll
                for (int tc = 0; tc < 4; ++tc)
#pragma unroll
                    for (int r = 0; r < 4; ++r) sa[fr][tc][r] = exp2f(sa[fr][tc][r]);
                float t0 = (sa[fr][0][0] + sa[fr][0][1]) + (sa[fr][0][2] + sa[fr][0][3]);
                float t1 = (sa[fr][1][0] + sa[fr][1][1]) + (sa[fr][1][2] + sa[fr][1][3]);
                float t2 = (sa[fr][2][0] + sa[fr][2][1]) + (sa[fr][2][2] + sa[fr][2][3]);
                float t3 = (sa[fr][3][0] + sa[fr][3][1]) + (sa[fr][3][2] + sa[fr][3][3]);
                lsum[fr] += (t0 + t1) + (t2 + t3);
#pragma unroll
                for (int tc = 0; tc < 4; ++tc) {
                    W[fr][tc][0] = cvt_pk_bf16(sa[fr][tc][0], sa[fr][tc][1]);
                    W[fr][tc][1] = cvt_pk_bf16(sa[fr][tc][2], sa[fr][tc][3]);
                }
            }

            // PV: redistribute P pairs in-register, then O += P * V^T
#pragma unroll
            for (int kb2 = 0; kb2 < 2; ++kb2) {
                bf16x8 pa[2];
#pragma unroll
                for (int fr = 0; fr < 2; ++fr) {
                    unsigned rA = W[fr][2 * kb2 + 0][0];
                    unsigned rB = W[fr][2 * kb2 + 0][1];
                    unsigned rC = W[fr][2 * kb2 + 1][0];
                    unsigned rD = W[fr][2 * kb2 + 1][1];
                    asm("v_permlane32_swap_b32 %0, %1" : "+v"(rA), "+v"(rC));
                    asm("v_permlane32_swap_b32 %0, %1" : "+v"(rB), "+v"(rD));
                    asm("v_permlane16_swap_b32 %0, %1" : "+v"(rA), "+v"(rC));
                    asm("v_permlane16_swap_b32 %0, %1" : "+v"(rB), "+v"(rD));
                    i32x4 wv = (i32x4){(int)rA, (int)rB, (int)rC, (int)rD};
                    pa[fr] = __builtin_bit_cast(bf16x8, wv);
                }
                __builtin_amdgcn_s_setprio(1);
#pragma unroll
                for (int t = 0; t < 8; ++t) {
                    bf16x8 vb = *(const bf16x8*)(VtB + hV + vA[kb2] + t * 4096);
                    ot[0][t] = __builtin_amdgcn_mfma_f32_16x16x32_bf16(pa[0], vb, ot[0][t], 0, 0, 0);
                    ot[1][t] = __builtin_amdgcn_mfma_f32_16x16x32_bf16(pa[1], vb, ot[1][t], 0, 0, 0);
                }
                __builtin_amdgcn_s_setprio(0);
            }
        }
    }

    // l reduction: sum partials over the 4 q-lane groups
#pragma unroll
    for (int fr = 0; fr < 2; ++fr) {
        lsum[fr] += __shfl_xor(lsum[fr], 16);
        lsum[fr] += __shfl_xor(lsum[fr], 32);
    }
    if (q == 0) {
#pragma unroll
        for (int fr = 0; fr < 2; ++fr) {
            size_t row = (size_t)half * BN_ + (size_t)b * N_ + n0 + wave * 32 + fr * 16 + s;
            lbuf[row] = lsum[fr];
        }
    }

    // scatter unnormalized f32 O (C-layout: row 4q+r, col t*16+s)
#pragma unroll
    for (int fr = 0; fr < 2; ++fr) {
        size_t rbase = (size_t)half * BN_ + (size_t)b * N_ + n0 + wave * 32 + fr * 16 + 4 * q;
#pragma unroll
        for (int t = 0; t < 8; ++t)
#pragma unroll
            for (int r = 0; r < 4; ++r)
                Op[(rbase + r) * I_ + t * 16 + s] = ot[fr][t][r];
    }
}

// ---- K3: fused merge + conv-out: wyh[B][C][N] bf16 = w_w @ ((O1+O2)/l) + w_b -
__global__ __launch_bounds__(256) void k_wy(const float* __restrict__ Op,
                                            const float* __restrict__ lbuf,
                                            const short* __restrict__ wwb,
                                            const float* __restrict__ w_b,
                                            short* __restrict__ wyh) {
    int b = blockIdx.y;
    int n0 = blockIdx.x * 64;
    int tid = threadIdx.x;
    int wave = tid >> 6, lane = tid & 63, s = lane & 15, q = lane >> 4;

    // per-(nt) row normalizer (row = b*N + n0 + nt*16 + s, fixed per lane)
    float linv[4];
#pragma unroll
    for (int nt = 0; nt < 4; ++nt) {
        size_t rn = (size_t)b * N_ + n0 + nt * 16 + s;
        linv[nt] = 1.0f / (lbuf[rn] + lbuf[(size_t)BN_ + rn]);
    }

    f32x4 acc[4][4];
#pragma unroll
    for (int ct = 0; ct < 4; ++ct)
#pragma unroll
        for (int nt = 0; nt < 4; ++nt) acc[ct][nt] = (f32x4){0.f, 0.f, 0.f, 0.f};
#pragma unroll
    for (int kb = 0; kb < 4; ++kb) {
        bf16x8 af[4], bfv[4];
#pragma unroll
        for (int ct = 0; ct < 4; ++ct)
            af[ct] = *(const bf16x8*)&wwb[(wave * 64 + ct * 16 + s) * 128 + kb * 32 + q * 8];
#pragma unroll
        for (int nt = 0; nt < 4; ++nt) {
            size_t rn = (size_t)b * N_ + n0 + nt * 16 + s;
            const float* p1 = Op + rn * I_ + kb * 32 + q * 8;
            const float* p2 = p1 + (size_t)BN_ * I_;
            float4 a0 = *(const float4*)p1;
            float4 a1 = *(const float4*)(p1 + 4);
            float4 b0 = *(const float4*)p2;
            float4 b1 = *(const float4*)(p2 + 4);
            short v[8];
            v[0] = f2bf((a0.x + b0.x) * linv[nt]);
            v[1] = f2bf((a0.y + b0.y) * linv[nt]);
            v[2] = f2bf((a0.z + b0.z) * linv[nt]);
            v[3] = f2bf((a0.w + b0.w) * linv[nt]);
            v[4] = f2bf((a1.x + b1.x) * linv[nt]);
            v[5] = f2bf((a1.y + b1.y) * linv[nt]);
            v[6] = f2bf((a1.z + b1.z) * linv[nt]);
            v[7] = f2bf((a1.w + b1.w) * linv[nt]);
            bfv[nt] = *(const bf16x8*)v;
        }
#pragma unroll
        for (int ct = 0; ct < 4; ++ct)
#pragma unroll
            for (int nt = 0; nt < 4; ++nt)
                acc[ct][nt] = __builtin_amdgcn_mfma_f32_16x16x32_bf16(af[ct], bfv[nt], acc[ct][nt], 0, 0, 0);
    }
#pragma unroll
    for (int ct = 0; ct < 4; ++ct)
#pragma unroll
        for (int nt = 0; nt < 4; ++nt)
#pragma unroll
            for (int r = 0; r < 4; ++r) {
                int c = wave * 64 + ct * 16 + 4 * q + r;
                int n = n0 + nt * 16 + s;
                wyh[((size_t)b * C_ + c) * N_ + n] = f2bf(acc[ct][nt][r] + w_b[c]);
            }
}

// ---------------- K4: BN stats from bf16 wy -> scale/shift ----------------
__global__ __launch_bounds__(256) void k_stats(const short* __restrict__ wyh,
                                               const float* __restrict__ gamma,
                                               const float* __restrict__ beta,
                                               float* __restrict__ scale,
                                               float* __restrict__ shift) {
    int c = blockIdx.x;
    int tid = threadIdx.x;
    float s1 = 0.f, s2 = 0.f;
    for (int b = 0; b < B_; ++b) {
        const short* p = wyh + ((size_t)b * C_ + c) * N_;
        for (int idx = tid * 8; idx < N_; idx += 2048) {
            bf16x8 v = *(const bf16x8*)&p[idx];
#pragma unroll
            for (int j = 0; j < 8; ++j) {
                float f = bf2f(v[j]);
                s1 += f;
                s2 += f * f;
            }
        }
    }
#pragma unroll
    for (int off = 1; off < 64; off <<= 1) {
        s1 += __shfl_xor(s1, off);
        s2 += __shfl_xor(s2, off);
    }
    __shared__ float r1[4], r2[4];
    if ((tid & 63) == 0) { r1[tid >> 6] = s1; r2[tid >> 6] = s2; }
    __syncthreads();
    if (tid == 0) {
        float t1 = r1[0] + r1[1] + r1[2] + r1[3];
        float t2 = r2[0] + r2[1] + r2[2] + r2[3];
        const float inv = 1.0f / 32768.0f;
        float mean = t1 * inv;
        float var = t2 * inv - mean * mean;
        float sc = gamma[c] * rsqrtf(var + 1e-5f);
        scale[c] = sc;
        shift[c] = beta[c] - mean * sc;
    }
}

// ---------------- K5: apply BN + residual -> d_out f32 ----------------
__global__ __launch_bounds__(256) void k_out(const short* __restrict__ wyh,
                                             const float* __restrict__ x,
                                             const float* __restrict__ scale,
                                             const float* __restrict__ shift,
                                             float* __restrict__ out) {
    int gid = blockIdx.x * 256 + threadIdx.x;  // 8-element group index
    size_t base = (size_t)gid * 8;
    int c = (int)((base >> 12) & 255);
    float sc = scale[c], sh = shift[c];
    bf16x8 w = *(const bf16x8*)&wyh[base];
    float4 x0 = *(const float4*)&x[base];
    float4 x1 = *(const float4*)&x[base + 4];
    float4 o0, o1;
    o0.x = bf2f(w[0]) * sc + sh + x0.x;
    o0.y = bf2f(w[1]) * sc + sh + x0.y;
    o0.z = bf2f(w[2]) * sc + sh + x0.z;
    o0.w = bf2f(w[3]) * sc + sh + x0.w;
    o1.x = bf2f(w[4]) * sc + sh + x1.x;
    o1.y = bf2f(w[5]) * sc + sh + x1.y;
    o1.z = bf2f(w[6]) * sc + sh + x1.z;
    o1.w = bf2f(w[7]) * sc + sh + x1.w;
    *(float4*)&out[base] = o0;
    *(float4*)&out[base + 4] = o1;
}

extern "C" void kernel_launch(void* const* d_in, const int* in_sizes, int n_in,
                              void* d_out, int out_size, void* d_ws, size_t ws_size,
                              hipStream_t stream) {
    const float* x       = (const float*)d_in[0];
    const float* g_w     = (const float*)d_in[1];
    const float* g_b     = (const float*)d_in[2];
    const float* theta_w = (const float*)d_in[3];
    const float* theta_b = (const float*)d_in[4];
    const float* phi_w   = (const float*)d_in[5];
    const float* phi_b   = (const float*)d_in[6];
    const float* w_w     = (const float*)d_in[7];
    const float* w_b     = (const float*)d_in[8];
    const float* gamma   = (const float*)d_in[9];
    const float* beta    = (const float*)d_in[10];

    char* ws = (char*)d_ws;
    size_t off = 0;
    auto alloc = [&](size_t bytes) {
        void* p = ws + off;
        off += (bytes + 255) & ~(size_t)255;
        return p;
    };
    // ws total ~42.3 MB (<= 52.2 MB proven in R3).
    short*  wcat  = (short*)alloc((size_t)384 * 256 * 2);
    short*  wwb   = (short*)alloc((size_t)256 * 128 * 2);
    float*  bcat  = (float*)alloc((size_t)384 * 4);
    float*  scale = (float*)alloc(256 * 4);
    float*  shift = (float*)alloc(256 * 4);
    short*  tp    = (short*)alloc((size_t)BN_ * 256 * 2);    // theta|phi 16.78 MB
    short*  gmat  = (short*)alloc((size_t)B_ * I_ * N_ * 2); // 8.39 MB
    short*  wyh   = (short*)alloc((size_t)BN_ * C_ * 2);     // bf16 wy 16.78 MB
    float*  lbuf  = (float*)alloc((size_t)2 * BN_ * 4);      // l sums 256 KB
    // Op (f32 split-K partials, 2*BN*I*4 = 33.55 MB) lives in d_out; k_wy
    // consumes it (reads d_out, writes wyh in ws - race-free); k_out then
    // overwrites d_out with the final result.
    float*  Op    = (float*)d_out;

    k_prep<<<514, 256, 0, stream>>>(g_w, theta_w, phi_w, g_b, theta_b, phi_b, w_w,
                                    wcat, wwb, bcat);
    k_proj<<<dim3(64, 8), 256, 0, stream>>>(x, wcat, bcat, tp, gmat);
    k_attn<<<512, 256, 0, stream>>>(tp, gmat, Op, lbuf);   // 8b x 32qt x 2half
    k_wy<<<dim3(64, 8), 256, 0, stream>>>(Op, lbuf, wwb, w_b, wyh);
    k_stats<<<256, 256, 0, stream>>>(wyh, gamma, beta, scale, shift);
    k_out<<<4096, 256, 0, stream>>>(wyh, x, scale, shift, (float*)d_out);
}

// Round 3
// 236.430 us; speedup vs baseline: 1.1241x; 1.1241x over previous
//
#include <hip/hip_runtime.h>

#define B_ 8
#define C_ 256
#define I_ 128
#define N_ 4096
#define BN_ (B_ * N_)
#define LOG2E 1.4426950408889634f

typedef __attribute__((ext_vector_type(8))) short bf16x8;
typedef __attribute__((ext_vector_type(4))) float f32x4;
typedef __attribute__((ext_vector_type(4))) int i32x4;

static __device__ __forceinline__ short f2bf(float f) {
    unsigned u = __float_as_uint(f);
    unsigned r = u + 0x7fffu + ((u >> 16) & 1u);  // RNE
    return (short)(r >> 16);
}
static __device__ __forceinline__ float bf2f(short s) {
    return __uint_as_float(((unsigned)(unsigned short)s) << 16);
}
static __device__ __forceinline__ unsigned cvt_pk_bf16(float lo, float hi) {
    unsigned r;
    asm("v_cvt_pk_bf16_f32 %0, %1, %2" : "=v"(r) : "v"(lo), "v"(hi));
    return r;
}

// ---------------- K0: weight prep (theta scaled by log2e) ----------------
__global__ void k_prep(const float* g_w, const float* theta_w, const float* phi_w,
                       const float* g_b, const float* theta_b, const float* phi_b,
                       const float* w_w, short* wcat, short* wwb, float* bcat) {
    int i = blockIdx.x * 256 + threadIdx.x;
    if (i < 384 * 256) {
        int j = i >> 8, c = i & 255;
        float v = (j < 128) ? theta_w[j * 256 + c] * LOG2E
                : (j < 256) ? phi_w[(j - 128) * 256 + c]
                            : g_w[(j - 256) * 256 + c];
        wcat[i] = f2bf(v);
    } else if (i < 384 * 256 + 256 * 128) {
        int k = i - 384 * 256;
        wwb[k] = f2bf(w_w[k]);
    } else if (i < 384 * 256 + 256 * 128 + 384) {
        int j = i - (384 * 256 + 256 * 128);
        bcat[j] = (j < 128) ? theta_b[j] * LOG2E
                : (j < 256) ? phi_b[j - 128] : g_b[j - 256];
    }
}

// ---------------- K1: projection -> tp[B][N][256], gmat[B][I][N] ---
__global__ __launch_bounds__(256) void k_proj(const float* __restrict__ x,
                                              const short* __restrict__ wcat,
                                              const float* __restrict__ bcat,
                                              short* __restrict__ tp,
                                              short* __restrict__ gmat) {
    int b = blockIdx.y;
    int n0 = blockIdx.x * 64;
    int tid = threadIdx.x;
    int wave = tid >> 6, lane = tid & 63, s = lane & 15, q = lane >> 4;
    __shared__ short xs[64][264];  // [n-local][c]

#pragma unroll
    for (int it = 0; it < 16; ++it) {
        int cr = (tid >> 4) + it * 16;
        int nc = tid & 15;
        const float4 v = *(const float4*)&x[((size_t)b * C_ + cr) * N_ + n0 + nc * 4];
        xs[nc * 4 + 0][cr] = f2bf(v.x);
        xs[nc * 4 + 1][cr] = f2bf(v.y);
        xs[nc * 4 + 2][cr] = f2bf(v.z);
        xs[nc * 4 + 3][cr] = f2bf(v.w);
    }
    __syncthreads();

    f32x4 acc[4][6];
#pragma unroll
    for (int rt = 0; rt < 4; ++rt)
#pragma unroll
        for (int jt = 0; jt < 6; ++jt) acc[rt][jt] = (f32x4){0.f, 0.f, 0.f, 0.f};

#pragma unroll
    for (int kb = 0; kb < 8; ++kb) {
        bf16x8 af[4], bfv[6];
#pragma unroll
        for (int rt = 0; rt < 4; ++rt)
            af[rt] = *(const bf16x8*)&xs[rt * 16 + s][kb * 32 + q * 8];
#pragma unroll
        for (int jt = 0; jt < 6; ++jt)
            bfv[jt] = *(const bf16x8*)&wcat[(wave * 96 + jt * 16 + s) * 256 + kb * 32 + q * 8];
#pragma unroll
        for (int rt = 0; rt < 4; ++rt)
#pragma unroll
            for (int jt = 0; jt < 6; ++jt)
                acc[rt][jt] = __builtin_amdgcn_mfma_f32_16x16x32_bf16(af[rt], bfv[jt], acc[rt][jt], 0, 0, 0);
    }

#pragma unroll
    for (int rt = 0; rt < 4; ++rt)
#pragma unroll
        for (int jt = 0; jt < 6; ++jt) {
            int j = wave * 96 + jt * 16 + s;
            float bias = bcat[j];
#pragma unroll
            for (int r = 0; r < 4; ++r) {
                int n = n0 + rt * 16 + 4 * q + r;
                float v = acc[rt][jt][r] + bias;
                if (j < 256)
                    tp[((size_t)b * N_ + n) * 256 + j] = f2bf(v);
                else
                    gmat[((size_t)b * I_ + (j - 256)) * N_ + n] = f2bf(v);
            }
        }
}

// ---- K2: fused flash attention + conv-out GEMM. NO split-K. -----------------
// 256 blocks x 512 threads (8 waves); each block: Q-tile 128 (16 q/wave),
// all 4096 keys, double-buffered 128KB LDS (1 barrier per 128-key tile).
// After key loop: block holds full unnormalized O + l -> y(bf16, unnorm) to
// LDS, then in-block wy GEMM (w_w from L2, 1/l folded into epilogue) -> wyh.
// Eliminates the Op f32 round-trip (33.5MB write + 67MB read) and k_wy.
__global__ __launch_bounds__(512, 2) void k_attn_wy(const short* __restrict__ tp,
                                                    const short* __restrict__ gmat,
                                                    const short* __restrict__ wwb,
                                                    const float* __restrict__ w_b,
                                                    short* __restrict__ wyh) {
    int id = blockIdx.x;
    int b = id & 7;               // XCD swizzle: one batch's K/V per XCD L2
    int qt = id >> 3;             // 0..31
    int n0 = qt * 128;
    int tid = threadIdx.x;
    int wave = tid >> 6, lane = tid & 63, s = lane & 15, q = lane >> 4;

    // 2 bufs x (Kt[128key][128i] 32KB + Vt[128i][128key] 32KB) = 128KB, swizzled
    __shared__ __align__(16) short SH[65536];
    __shared__ float l_lds[128];
    char* base = (char*)SH;

    const int swz = (s & 7) << 4;
    int kA[4];
#pragma unroll
    for (int kb = 0; kb < 4; ++kb) kA[kb] = s * 256 + ((kb * 64 + q * 16) ^ swz);
    int vA[2];
#pragma unroll
    for (int kb2 = 0; kb2 < 2; ++kb2) vA[kb2] = s * 256 + ((kb2 * 64 + q * 16) ^ swz);
    int krow = tid >> 4, kch = tid & 15;  // staging: 32 rows x 16 chunks
    int stW = krow * 256 + ((kch * 16) ^ ((krow & 7) << 4));

    // Q fragments (B-operand of S^T): queries n0 + wave*16 + s
    bf16x8 qf[4];
    {
        const short* qb = tp + ((size_t)b * N_ + n0 + wave * 16 + s) * 256;
#pragma unroll
        for (int kb = 0; kb < 4; ++kb) qf[kb] = *(const bf16x8*)(qb + kb * 32 + q * 8);
    }

    f32x4 ot[8];  // O: rows=query 4q+r (within wave's 16), cols i = t*16+s
#pragma unroll
    for (int t = 0; t < 8; ++t) ot[t] = (f32x4){0.f, 0.f, 0.f, 0.f};
    float lsum = 0.f;  // per-lane l partial for query wave*16+s

    // prologue: stage tile 0 into buf0
    bf16x8 pk[4], pv[4];
#pragma unroll
    for (int it = 0; it < 4; ++it) {
        pk[it] = *(const bf16x8*)&tp[((size_t)b * N_ + krow + it * 32) * 256 + 128 + kch * 8];
        pv[it] = *(const bf16x8*)&gmat[((size_t)b * I_ + krow + it * 32) * N_ + kch * 8];
    }
#pragma unroll
    for (int it = 0; it < 4; ++it) {
        *(bf16x8*)(base + stW + it * 8192) = pk[it];
        *(bf16x8*)(base + 32768 + stW + it * 8192) = pv[it];
    }
    __syncthreads();

    for (int i = 0; i < 32; ++i) {
        char* KtB = base + (i & 1) * 65536;
        char* VtB = KtB + 32768;
        if (i < 31) {  // issue next-tile loads early; latency hides under compute
            int m = (i + 1) * 128;
#pragma unroll
            for (int it = 0; it < 4; ++it) {
                pk[it] = *(const bf16x8*)&tp[((size_t)b * N_ + m + krow + it * 32) * 256 + 128 + kch * 8];
                pv[it] = *(const bf16x8*)&gmat[((size_t)b * I_ + krow + it * 32) * N_ + m + kch * 8];
            }
        }

#pragma unroll
        for (int h = 0; h < 2; ++h) {   // two 64-key sub-tiles
            const int hK = h * 16384, hV = h * 128;

            // S^T = mfma(K, Q): D[row=key tc*16+4q+r][col=query s]
            f32x4 sa[4];
#pragma unroll
            for (int tc = 0; tc < 4; ++tc) sa[tc] = (f32x4){0.f, 0.f, 0.f, 0.f};
            __builtin_amdgcn_s_setprio(1);
#pragma unroll
            for (int tc = 0; tc < 4; ++tc) {
#pragma unroll
                for (int kb = 0; kb < 4; ++kb) {
                    bf16x8 bfv = *(const bf16x8*)(KtB + hK + kA[kb] + tc * 4096);
                    sa[tc] = __builtin_amdgcn_mfma_f32_16x16x32_bf16(bfv, qf[kb], sa[tc], 0, 0, 0);
                }
            }
            __builtin_amdgcn_s_setprio(0);

            // P = exp2(S), l accumulation, pack pairs
#pragma unroll
            for (int tc = 0; tc < 4; ++tc)
#pragma unroll
                for (int r = 0; r < 4; ++r) sa[tc][r] = exp2f(sa[tc][r]);
            {
                float t0 = (sa[0][0] + sa[0][1]) + (sa[0][2] + sa[0][3]);
                float t1 = (sa[1][0] + sa[1][1]) + (sa[1][2] + sa[1][3]);
                float t2 = (sa[2][0] + sa[2][1]) + (sa[2][2] + sa[2][3]);
                float t3 = (sa[3][0] + sa[3][1]) + (sa[3][2] + sa[3][3]);
                lsum += (t0 + t1) + (t2 + t3);
            }
            unsigned W[4][2];
#pragma unroll
            for (int tc = 0; tc < 4; ++tc) {
                W[tc][0] = cvt_pk_bf16(sa[tc][0], sa[tc][1]);
                W[tc][1] = cvt_pk_bf16(sa[tc][2], sa[tc][3]);
            }

            // PV: redistribute P pairs in-register, then O += P * V^T
#pragma unroll
            for (int kb2 = 0; kb2 < 2; ++kb2) {
                unsigned rA = W[2 * kb2 + 0][0];
                unsigned rB = W[2 * kb2 + 0][1];
                unsigned rC = W[2 * kb2 + 1][0];
                unsigned rD = W[2 * kb2 + 1][1];
                asm("v_permlane32_swap_b32 %0, %1" : "+v"(rA), "+v"(rC));
                asm("v_permlane32_swap_b32 %0, %1" : "+v"(rB), "+v"(rD));
                asm("v_permlane16_swap_b32 %0, %1" : "+v"(rA), "+v"(rC));
                asm("v_permlane16_swap_b32 %0, %1" : "+v"(rB), "+v"(rD));
                i32x4 wv = (i32x4){(int)rA, (int)rB, (int)rC, (int)rD};
                bf16x8 pa = __builtin_bit_cast(bf16x8, wv);
                __builtin_amdgcn_s_setprio(1);
#pragma unroll
                for (int t = 0; t < 8; ++t) {
                    bf16x8 vb = *(const bf16x8*)(VtB + hV + vA[kb2] + t * 4096);
                    ot[t] = __builtin_amdgcn_mfma_f32_16x16x32_bf16(pa, vb, ot[t], 0, 0, 0);
                }
                __builtin_amdgcn_s_setprio(0);
            }
        }

        if (i < 31) {  // write next tile into other buffer
            char* KtN = base + ((i & 1) ^ 1) * 65536;
#pragma unroll
            for (int it = 0; it < 4; ++it) {
                *(bf16x8*)(KtN + stW + it * 8192) = pk[it];
                *(bf16x8*)(KtN + 32768 + stW + it * 8192) = pv[it];
            }
        }
        __syncthreads();
    }

    // ---- epilogue: l, y->LDS, in-block wy GEMM ----
    lsum += __shfl_xor(lsum, 16);
    lsum += __shfl_xor(lsum, 32);
    if (lane < 16) l_lds[wave * 16 + s] = lsum;

    // unnormalized y bf16 -> LDS [128 n][128 i] swizzled (reuse buf0 region)
#pragma unroll
    for (int t = 0; t < 8; ++t)
#pragma unroll
        for (int r = 0; r < 4; ++r) {
            int row = wave * 16 + 4 * q + r;
            int byt = row * 256 + (((t * 16 + s) * 2) ^ ((row & 7) << 4));
            *(short*)(base + byt) = f2bf(ot[t][r]);
        }
    __syncthreads();

    // wy GEMM: c = wave*32 + ct*16 + {s|4q+r}, n = n0 + jt*16 + s
    f32x4 acc[2][8];
#pragma unroll
    for (int ct = 0; ct < 2; ++ct)
#pragma unroll
        for (int jt = 0; jt < 8; ++jt) acc[ct][jt] = (f32x4){0.f, 0.f, 0.f, 0.f};
#pragma unroll
    for (int kb = 0; kb < 4; ++kb) {
        bf16x8 af[2];
#pragma unroll
        for (int ct = 0; ct < 2; ++ct)
            af[ct] = *(const bf16x8*)&wwb[(wave * 32 + ct * 16 + s) * 128 + kb * 32 + q * 8];
#pragma unroll
        for (int jt = 0; jt < 8; ++jt) {
            bf16x8 yb = *(const bf16x8*)(base + kA[kb] + jt * 4096);
#pragma unroll
            for (int ct = 0; ct < 2; ++ct)
                acc[ct][jt] = __builtin_amdgcn_mfma_f32_16x16x32_bf16(af[ct], yb, acc[ct][jt], 0, 0, 0);
        }
    }
    float linv[8];
#pragma unroll
    for (int jt = 0; jt < 8; ++jt) linv[jt] = 1.0f / l_lds[jt * 16 + s];
#pragma unroll
    for (int ct = 0; ct < 2; ++ct)
#pragma unroll
        for (int r = 0; r < 4; ++r) {
            int c = wave * 32 + ct * 16 + 4 * q + r;
            float bias = w_b[c];
#pragma unroll
            for (int jt = 0; jt < 8; ++jt)
                wyh[((size_t)b * C_ + c) * N_ + n0 + jt * 16 + s] =
                    f2bf(acc[ct][jt][r] * linv[jt] + bias);
        }
}

// ---------------- K4: BN stats from bf16 wy -> scale/shift ----------------
__global__ __launch_bounds__(256) void k_stats(const short* __restrict__ wyh,
                                               const float* __restrict__ gamma,
                                               const float* __restrict__ beta,
                                               float* __restrict__ scale,
                                               float* __restrict__ shift) {
    int c = blockIdx.x;
    int tid = threadIdx.x;
    float s1 = 0.f, s2 = 0.f;
    for (int b = 0; b < B_; ++b) {
        const short* p = wyh + ((size_t)b * C_ + c) * N_;
        for (int idx = tid * 8; idx < N_; idx += 2048) {
            bf16x8 v = *(const bf16x8*)&p[idx];
#pragma unroll
            for (int j = 0; j < 8; ++j) {
                float f = bf2f(v[j]);
                s1 += f;
                s2 += f * f;
            }
        }
    }
#pragma unroll
    for (int off = 1; off < 64; off <<= 1) {
        s1 += __shfl_xor(s1, off);
        s2 += __shfl_xor(s2, off);
    }
    __shared__ float r1[4], r2[4];
    if ((tid & 63) == 0) { r1[tid >> 6] = s1; r2[tid >> 6] = s2; }
    __syncthreads();
    if (tid == 0) {
        float t1 = r1[0] + r1[1] + r1[2] + r1[3];
        float t2 = r2[0] + r2[1] + r2[2] + r2[3];
        const float inv = 1.0f / 32768.0f;
        float mean = t1 * inv;
        float var = t2 * inv - mean * mean;
        float sc = gamma[c] * rsqrtf(var + 1e-5f);
        scale[c] = sc;
        shift[c] = beta[c] - mean * sc;
    }
}

// ---------------- K5: apply BN + residual -> d_out f32 ----------------
__global__ __launch_bounds__(256) void k_out(const short* __restrict__ wyh,
                                             const float* __restrict__ x,
                                             const float* __restrict__ scale,
                                             const float* __restrict__ shift,
                                             float* __restrict__ out) {
    int gid = blockIdx.x * 256 + threadIdx.x;  // 8-element group index
    size_t base = (size_t)gid * 8;
    int c = (int)((base >> 12) & 255);
    float sc = scale[c], sh = shift[c];
    bf16x8 w = *(const bf16x8*)&wyh[base];
    float4 x0 = *(const float4*)&x[base];
    float4 x1 = *(const float4*)&x[base + 4];
    float4 o0, o1;
    o0.x = bf2f(w[0]) * sc + sh + x0.x;
    o0.y = bf2f(w[1]) * sc + sh + x0.y;
    o0.z = bf2f(w[2]) * sc + sh + x0.z;
    o0.w = bf2f(w[3]) * sc + sh + x0.w;
    o1.x = bf2f(w[4]) * sc + sh + x1.x;
    o1.y = bf2f(w[5]) * sc + sh + x1.y;
    o1.z = bf2f(w[6]) * sc + sh + x1.z;
    o1.w = bf2f(w[7]) * sc + sh + x1.w;
    *(float4*)&out[base] = o0;
    *(float4*)&out[base + 4] = o1;
}

extern "C" void kernel_launch(void* const* d_in, const int* in_sizes, int n_in,
                              void* d_out, int out_size, void* d_ws, size_t ws_size,
                              hipStream_t stream) {
    const float* x       = (const float*)d_in[0];
    const float* g_w     = (const float*)d_in[1];
    const float* g_b     = (const float*)d_in[2];
    const float* theta_w = (const float*)d_in[3];
    const float* theta_b = (const float*)d_in[4];
    const float* phi_w   = (const float*)d_in[5];
    const float* phi_b   = (const float*)d_in[6];
    const float* w_w     = (const float*)d_in[7];
    const float* w_b     = (const float*)d_in[8];
    const float* gamma   = (const float*)d_in[9];
    const float* beta    = (const float*)d_in[10];

    char* ws = (char*)d_ws;
    size_t off = 0;
    auto alloc = [&](size_t bytes) {
        void* p = ws + off;
        off += (bytes + 255) & ~(size_t)255;
        return p;
    };
    short*  wcat  = (short*)alloc((size_t)384 * 256 * 2);
    short*  wwb   = (short*)alloc((size_t)256 * 128 * 2);
    float*  bcat  = (float*)alloc((size_t)384 * 4);
    float*  scale = (float*)alloc(256 * 4);
    float*  shift = (float*)alloc(256 * 4);
    short*  tp    = (short*)alloc((size_t)BN_ * 256 * 2);    // theta|phi 16.78 MB
    short*  gmat  = (short*)alloc((size_t)B_ * I_ * N_ * 2); // 8.39 MB
    short*  wyh   = (short*)alloc((size_t)BN_ * C_ * 2);     // bf16 wy 16.78 MB

    k_prep<<<514, 256, 0, stream>>>(g_w, theta_w, phi_w, g_b, theta_b, phi_b, w_w,
                                    wcat, wwb, bcat);
    k_proj<<<dim3(64, 8), 256, 0, stream>>>(x, wcat, bcat, tp, gmat);
    k_attn_wy<<<256, 512, 0, stream>>>(tp, gmat, wwb, w_b, wyh);  // 8b x 32qt
    k_stats<<<256, 256, 0, stream>>>(wyh, gamma, beta, scale, shift);
    k_out<<<4096, 256, 0, stream>>>(wyh, x, scale, shift, (float*)d_out);
}

// Round 4
// 227.198 us; speedup vs baseline: 1.1698x; 1.0406x over previous
//
#include <hip/hip_runtime.h>

#define B_ 8
#define C_ 256
#define I_ 128
#define N_ 4096
#define BN_ (B_ * N_)
#define LOG2E 1.4426950408889634f

typedef __attribute__((ext_vector_type(8))) short bf16x8;
typedef __attribute__((ext_vector_type(4))) float f32x4;
typedef __attribute__((ext_vector_type(4))) int i32x4;

static __device__ __forceinline__ short f2bf(float f) {
    unsigned u = __float_as_uint(f);
    unsigned r = u + 0x7fffu + ((u >> 16) & 1u);  // RNE
    return (short)(r >> 16);
}
static __device__ __forceinline__ float bf2f(short s) {
    return __uint_as_float(((unsigned)(unsigned short)s) << 16);
}
static __device__ __forceinline__ unsigned cvt_pk_bf16(float lo, float hi) {
    unsigned r;
    asm("v_cvt_pk_bf16_f32 %0, %1, %2" : "=v"(r) : "v"(lo), "v"(hi));
    return r;
}

// ---------------- K0: weight prep (theta scaled by log2e) ----------------
__global__ void k_prep(const float* g_w, const float* theta_w, const float* phi_w,
                       const float* g_b, const float* theta_b, const float* phi_b,
                       const float* w_w, short* wcat, short* wwb, float* bcat) {
    int i = blockIdx.x * 256 + threadIdx.x;
    if (i < 384 * 256) {
        int j = i >> 8, c = i & 255;
        float v = (j < 128) ? theta_w[j * 256 + c] * LOG2E
                : (j < 256) ? phi_w[(j - 128) * 256 + c]
                            : g_w[(j - 256) * 256 + c];
        wcat[i] = f2bf(v);
    } else if (i < 384 * 256 + 256 * 128) {
        int k = i - 384 * 256;
        wwb[k] = f2bf(w_w[k]);
    } else if (i < 384 * 256 + 256 * 128 + 384) {
        int j = i - (384 * 256 + 256 * 128);
        bcat[j] = (j < 128) ? theta_b[j] * LOG2E
                : (j < 256) ? phi_b[j - 128] : g_b[j - 256];
    }
}

// ---------------- K1: projection -> tp[B][N][256], gmat[B][I][N] ---
__global__ __launch_bounds__(256) void k_proj(const float* __restrict__ x,
                                              const short* __restrict__ wcat,
                                              const float* __restrict__ bcat,
                                              short* __restrict__ tp,
                                              short* __restrict__ gmat) {
    int b = blockIdx.y;
    int n0 = blockIdx.x * 64;
    int tid = threadIdx.x;
    int wave = tid >> 6, lane = tid & 63, s = lane & 15, q = lane >> 4;
    __shared__ short xs[64][264];  // [n-local][c]

#pragma unroll
    for (int it = 0; it < 16; ++it) {
        int cr = (tid >> 4) + it * 16;
        int nc = tid & 15;
        const float4 v = *(const float4*)&x[((size_t)b * C_ + cr) * N_ + n0 + nc * 4];
        xs[nc * 4 + 0][cr] = f2bf(v.x);
        xs[nc * 4 + 1][cr] = f2bf(v.y);
        xs[nc * 4 + 2][cr] = f2bf(v.z);
        xs[nc * 4 + 3][cr] = f2bf(v.w);
    }
    __syncthreads();

    f32x4 acc[4][6];
#pragma unroll
    for (int rt = 0; rt < 4; ++rt)
#pragma unroll
        for (int jt = 0; jt < 6; ++jt) acc[rt][jt] = (f32x4){0.f, 0.f, 0.f, 0.f};

#pragma unroll
    for (int kb = 0; kb < 8; ++kb) {
        bf16x8 af[4], bfv[6];
#pragma unroll
        for (int rt = 0; rt < 4; ++rt)
            af[rt] = *(const bf16x8*)&xs[rt * 16 + s][kb * 32 + q * 8];
#pragma unroll
        for (int jt = 0; jt < 6; ++jt)
            bfv[jt] = *(const bf16x8*)&wcat[(wave * 96 + jt * 16 + s) * 256 + kb * 32 + q * 8];
#pragma unroll
        for (int rt = 0; rt < 4; ++rt)
#pragma unroll
            for (int jt = 0; jt < 6; ++jt)
                acc[rt][jt] = __builtin_amdgcn_mfma_f32_16x16x32_bf16(af[rt], bfv[jt], acc[rt][jt], 0, 0, 0);
    }

#pragma unroll
    for (int rt = 0; rt < 4; ++rt)
#pragma unroll
        for (int jt = 0; jt < 6; ++jt) {
            int j = wave * 96 + jt * 16 + s;
            float bias = bcat[j];
#pragma unroll
            for (int r = 0; r < 4; ++r) {
                int n = n0 + rt * 16 + 4 * q + r;
                float v = acc[rt][jt][r] + bias;
                if (j < 256)
                    tp[((size_t)b * N_ + n) * 256 + j] = f2bf(v);
                else
                    gmat[((size_t)b * I_ + (j - 256)) * N_ + n] = f2bf(v);
            }
        }
}

// ---- K2: fused flash attention + conv-out GEMM. NO split-K. -----------------
// 256 blocks x 512 threads; Q-tile 128, all 4096 keys, dbuf 128KB LDS.
// Wave layout G_q=4 x G_k=2: wave = kg*4 + qg. Each wave: 32 queries (fr=2),
// its 64-key half of each 128-key tile. Halves per-wave LDS reads vs fr=1
// (K-frags amortized over 2 fr). l accumulated via MFMA against ones B-frag
// (off the VALU critical path). Epilogue: kg=1 dumps O-partials+l to LDS,
// kg=0 adds + writes y bf16, then 8-wave in-block wy GEMM -> wyh.
__global__ __launch_bounds__(512, 2) void k_attn_wy(const short* __restrict__ tp,
                                                    const short* __restrict__ gmat,
                                                    const short* __restrict__ wwb,
                                                    const float* __restrict__ w_b,
                                                    short* __restrict__ wyh) {
    int id = blockIdx.x;
    int b = id & 7;               // XCD swizzle: one batch's K/V per XCD L2
    int qt = id >> 3;             // 0..31
    int n0 = qt * 128;
    int tid = threadIdx.x;
    int wave = tid >> 6, lane = tid & 63, s = lane & 15, q = lane >> 4;
    int kg = wave >> 2, qg = wave & 3;

    // 2 bufs x (Kt[128key][128i] 32KB + Vt[128i][128key] 32KB) = 128KB, swizzled
    __shared__ __align__(16) short SH[65536];
    __shared__ float l_lds[2][128];
    char* base = (char*)SH;

    const int swz = (s & 7) << 4;
    int kA[4];
#pragma unroll
    for (int kb = 0; kb < 4; ++kb) kA[kb] = s * 256 + ((kb * 64 + q * 16) ^ swz);
    int vA[2];
#pragma unroll
    for (int kb2 = 0; kb2 < 2; ++kb2) vA[kb2] = s * 256 + ((kb2 * 64 + q * 16) ^ swz);
    int krow = tid >> 4, kch = tid & 15;  // staging: 32 rows x 16 chunks
    int stW = krow * 256 + ((kch * 16) ^ ((krow & 7) << 4));

    // ones B-frag for l-accumulation MFMA
    i32x4 onesw = (i32x4){0x3F803F80, 0x3F803F80, 0x3F803F80, 0x3F803F80};
    bf16x8 vone = __builtin_bit_cast(bf16x8, onesw);

    // Q fragments (B-operand of S^T): queries n0 + qg*32 + fr*16 + s
    bf16x8 qf[2][4];
#pragma unroll
    for (int fr = 0; fr < 2; ++fr) {
        const short* qb = tp + ((size_t)b * N_ + n0 + qg * 32 + fr * 16 + s) * 256;
#pragma unroll
        for (int kb = 0; kb < 4; ++kb) qf[fr][kb] = *(const bf16x8*)(qb + kb * 32 + q * 8);
    }

    f32x4 ot[2][8];  // O partial (kg's key half): rows=query 4q+r, cols i=t*16+s
#pragma unroll
    for (int fr = 0; fr < 2; ++fr)
#pragma unroll
        for (int t = 0; t < 8; ++t) ot[fr][t] = (f32x4){0.f, 0.f, 0.f, 0.f};
    f32x4 lacc[2] = {(f32x4){0.f, 0.f, 0.f, 0.f}, (f32x4){0.f, 0.f, 0.f, 0.f}};

    // prologue: stage tile 0 into buf0
    bf16x8 pk[4], pv[4];
#pragma unroll
    for (int it = 0; it < 4; ++it) {
        pk[it] = *(const bf16x8*)&tp[((size_t)b * N_ + krow + it * 32) * 256 + 128 + kch * 8];
        pv[it] = *(const bf16x8*)&gmat[((size_t)b * I_ + krow + it * 32) * N_ + kch * 8];
    }
#pragma unroll
    for (int it = 0; it < 4; ++it) {
        *(bf16x8*)(base + stW + it * 8192) = pk[it];
        *(bf16x8*)(base + 32768 + stW + it * 8192) = pv[it];
    }
    __syncthreads();

    const int hK = kg * 16384, hV = kg * 128;  // this wave's 64-key half

    for (int i = 0; i < 32; ++i) {
        char* KtB = base + (i & 1) * 65536;
        char* VtB = KtB + 32768;
        if (i < 31) {  // issue next-tile loads early; latency hides under compute
            int m = (i + 1) * 128;
#pragma unroll
            for (int it = 0; it < 4; ++it) {
                pk[it] = *(const bf16x8*)&tp[((size_t)b * N_ + m + krow + it * 32) * 256 + 128 + kch * 8];
                pv[it] = *(const bf16x8*)&gmat[((size_t)b * I_ + krow + it * 32) * N_ + m + kch * 8];
            }
        }

        // S^T = mfma(K, Q): D[row=key kg*64+tc*16+4q+r][col=query s]
        f32x4 sa[2][4];
#pragma unroll
        for (int fr = 0; fr < 2; ++fr)
#pragma unroll
            for (int tc = 0; tc < 4; ++tc) sa[fr][tc] = (f32x4){0.f, 0.f, 0.f, 0.f};
        __builtin_amdgcn_s_setprio(1);
#pragma unroll
        for (int tc = 0; tc < 4; ++tc) {
            bf16x8 bfv[4];
#pragma unroll
            for (int kb = 0; kb < 4; ++kb)
                bfv[kb] = *(const bf16x8*)(KtB + hK + kA[kb] + tc * 4096);
#pragma unroll
            for (int fr = 0; fr < 2; ++fr)
#pragma unroll
                for (int kb = 0; kb < 4; ++kb)
                    sa[fr][tc] = __builtin_amdgcn_mfma_f32_16x16x32_bf16(bfv[kb], qf[fr][kb], sa[fr][tc], 0, 0, 0);
        }
        __builtin_amdgcn_s_setprio(0);

        // P = exp2(S), pack pairs (keys 2p,2p+1)
        unsigned W[2][4][2];
#pragma unroll
        for (int fr = 0; fr < 2; ++fr) {
#pragma unroll
            for (int tc = 0; tc < 4; ++tc)
#pragma unroll
                for (int r = 0; r < 4; ++r) sa[fr][tc][r] = exp2f(sa[fr][tc][r]);
#pragma unroll
            for (int tc = 0; tc < 4; ++tc) {
                W[fr][tc][0] = cvt_pk_bf16(sa[fr][tc][0], sa[fr][tc][1]);
                W[fr][tc][1] = cvt_pk_bf16(sa[fr][tc][2], sa[fr][tc][3]);
            }
        }

        // PV: redistribute P pairs in-register; l via ones-MFMA; O += P*V^T
#pragma unroll
        for (int kb2 = 0; kb2 < 2; ++kb2) {
            bf16x8 pa[2];
#pragma unroll
            for (int fr = 0; fr < 2; ++fr) {
                unsigned rA = W[fr][2 * kb2 + 0][0];
                unsigned rB = W[fr][2 * kb2 + 0][1];
                unsigned rC = W[fr][2 * kb2 + 1][0];
                unsigned rD = W[fr][2 * kb2 + 1][1];
                asm("v_permlane32_swap_b32 %0, %1" : "+v"(rA), "+v"(rC));
                asm("v_permlane32_swap_b32 %0, %1" : "+v"(rB), "+v"(rD));
                asm("v_permlane16_swap_b32 %0, %1" : "+v"(rA), "+v"(rC));
                asm("v_permlane16_swap_b32 %0, %1" : "+v"(rB), "+v"(rD));
                i32x4 wv = (i32x4){(int)rA, (int)rB, (int)rC, (int)rD};
                pa[fr] = __builtin_bit_cast(bf16x8, wv);
            }
            __builtin_amdgcn_s_setprio(1);
            lacc[0] = __builtin_amdgcn_mfma_f32_16x16x32_bf16(pa[0], vone, lacc[0], 0, 0, 0);
            lacc[1] = __builtin_amdgcn_mfma_f32_16x16x32_bf16(pa[1], vone, lacc[1], 0, 0, 0);
#pragma unroll
            for (int t = 0; t < 8; ++t) {
                bf16x8 vb = *(const bf16x8*)(VtB + hV + vA[kb2] + t * 4096);
                ot[0][t] = __builtin_amdgcn_mfma_f32_16x16x32_bf16(pa[0], vb, ot[0][t], 0, 0, 0);
                ot[1][t] = __builtin_amdgcn_mfma_f32_16x16x32_bf16(pa[1], vb, ot[1][t], 0, 0, 0);
            }
            __builtin_amdgcn_s_setprio(0);
        }

        if (i < 31) {  // write next tile into other buffer
            char* KtN = base + ((i & 1) ^ 1) * 65536;
#pragma unroll
            for (int it = 0; it < 4; ++it) {
                *(bf16x8*)(KtN + stW + it * 8192) = pk[it];
                *(bf16x8*)(KtN + 32768 + stW + it * 8192) = pv[it];
            }
        }
        __syncthreads();
    }

    // ---- epilogue: cross-kg O reduction, y->LDS, in-block wy GEMM ----
    // l: all cols of lacc are equal; lane s==0 publishes rows 4q+r
    if (s == 0) {
#pragma unroll
        for (int fr = 0; fr < 2; ++fr)
#pragma unroll
            for (int r = 0; r < 4; ++r)
                l_lds[kg][qg * 32 + fr * 16 + 4 * q + r] = lacc[fr][r];
    }
    // kg=1 dumps O partials (f32, swizzled 16B blocks) into base[0..64KB)
    if (kg == 1) {
#pragma unroll
        for (int fr = 0; fr < 2; ++fr)
#pragma unroll
            for (int t = 0; t < 8; ++t)
#pragma unroll
                for (int r = 0; r < 4; ++r) {
                    int row = qg * 32 + fr * 16 + 4 * q + r;
                    int colb = (t * 16 + s) * 4;
                    *(float*)(base + row * 512 + (colb ^ ((row & 7) << 4))) = ot[fr][t][r];
                }
    }
    __syncthreads();
    // kg=0 adds partials, writes unnormalized y bf16 -> base[65536..98304)
    if (kg == 0) {
#pragma unroll
        for (int fr = 0; fr < 2; ++fr)
#pragma unroll
            for (int t = 0; t < 8; ++t)
#pragma unroll
                for (int r = 0; r < 4; ++r) {
                    int row = qg * 32 + fr * 16 + 4 * q + r;
                    int colb = (t * 16 + s) * 4;
                    float p = *(const float*)(base + row * 512 + (colb ^ ((row & 7) << 4)));
                    float v = ot[fr][t][r] + p;
                    int byt = 65536 + row * 256 + (((t * 16 + s) * 2) ^ ((row & 7) << 4));
                    *(short*)(base + byt) = f2bf(v);
                }
    }
    __syncthreads();

    // wy GEMM: c = wave*32 + ct*16 + {s|4q+r}, n = n0 + jt*16 + s
    f32x4 acc[2][8];
#pragma unroll
    for (int ct = 0; ct < 2; ++ct)
#pragma unroll
        for (int jt = 0; jt < 8; ++jt) acc[ct][jt] = (f32x4){0.f, 0.f, 0.f, 0.f};
#pragma unroll
    for (int kb = 0; kb < 4; ++kb) {
        bf16x8 af[2];
#pragma unroll
        for (int ct = 0; ct < 2; ++ct)
            af[ct] = *(const bf16x8*)&wwb[(wave * 32 + ct * 16 + s) * 128 + kb * 32 + q * 8];
#pragma unroll
        for (int jt = 0; jt < 8; ++jt) {
            bf16x8 yb = *(const bf16x8*)(base + 65536 + kA[kb] + jt * 4096);
#pragma unroll
            for (int ct = 0; ct < 2; ++ct)
                acc[ct][jt] = __builtin_amdgcn_mfma_f32_16x16x32_bf16(af[ct], yb, acc[ct][jt], 0, 0, 0);
        }
    }
    float linv[8];
#pragma unroll
    for (int jt = 0; jt < 8; ++jt)
        linv[jt] = 1.0f / (l_lds[0][jt * 16 + s] + l_lds[1][jt * 16 + s]);
#pragma unroll
    for (int ct = 0; ct < 2; ++ct)
#pragma unroll
        for (int r = 0; r < 4; ++r) {
            int c = wave * 32 + ct * 16 + 4 * q + r;
            float bias = w_b[c];
#pragma unroll
            for (int jt = 0; jt < 8; ++jt)
                wyh[((size_t)b * C_ + c) * N_ + n0 + jt * 16 + s] =
                    f2bf(acc[ct][jt][r] * linv[jt] + bias);
        }
}

// ---------------- K4: BN stats from bf16 wy -> scale/shift ----------------
__global__ __launch_bounds__(256) void k_stats(const short* __restrict__ wyh,
                                               const float* __restrict__ gamma,
                                               const float* __restrict__ beta,
                                               float* __restrict__ scale,
                                               float* __restrict__ shift) {
    int c = blockIdx.x;
    int tid = threadIdx.x;
    float s1 = 0.f, s2 = 0.f;
    for (int b = 0; b < B_; ++b) {
        const short* p = wyh + ((size_t)b * C_ + c) * N_;
        for (int idx = tid * 8; idx < N_; idx += 2048) {
            bf16x8 v = *(const bf16x8*)&p[idx];
#pragma unroll
            for (int j = 0; j < 8; ++j) {
                float f = bf2f(v[j]);
                s1 += f;
                s2 += f * f;
            }
        }
    }
#pragma unroll
    for (int off = 1; off < 64; off <<= 1) {
        s1 += __shfl_xor(s1, off);
        s2 += __shfl_xor(s2, off);
    }
    __shared__ float r1[4], r2[4];
    if ((tid & 63) == 0) { r1[tid >> 6] = s1; r2[tid >> 6] = s2; }
    __syncthreads();
    if (tid == 0) {
        float t1 = r1[0] + r1[1] + r1[2] + r1[3];
        float t2 = r2[0] + r2[1] + r2[2] + r2[3];
        const float inv = 1.0f / 32768.0f;
        float mean = t1 * inv;
        float var = t2 * inv - mean * mean;
        float sc = gamma[c] * rsqrtf(var + 1e-5f);
        scale[c] = sc;
        shift[c] = beta[c] - mean * sc;
    }
}

// ---------------- K5: apply BN + residual -> d_out f32 ----------------
__global__ __launch_bounds__(256) void k_out(const short* __restrict__ wyh,
                                             const float* __restrict__ x,
                                             const float* __restrict__ scale,
                                             const float* __restrict__ shift,
                                             float* __restrict__ out) {
    int gid = blockIdx.x * 256 + threadIdx.x;  // 8-element group index
    size_t base = (size_t)gid * 8;
    int c = (int)((base >> 12) & 255);
    float sc = scale[c], sh = shift[c];
    bf16x8 w = *(const bf16x8*)&wyh[base];
    float4 x0 = *(const float4*)&x[base];
    float4 x1 = *(const float4*)&x[base + 4];
    float4 o0, o1;
    o0.x = bf2f(w[0]) * sc + sh + x0.x;
    o0.y = bf2f(w[1]) * sc + sh + x0.y;
    o0.z = bf2f(w[2]) * sc + sh + x0.z;
    o0.w = bf2f(w[3]) * sc + sh + x0.w;
    o1.x = bf2f(w[4]) * sc + sh + x1.x;
    o1.y = bf2f(w[5]) * sc + sh + x1.y;
    o1.z = bf2f(w[6]) * sc + sh + x1.z;
    o1.w = bf2f(w[7]) * sc + sh + x1.w;
    *(float4*)&out[base] = o0;
    *(float4*)&out[base + 4] = o1;
}

extern "C" void kernel_launch(void* const* d_in, const int* in_sizes, int n_in,
                              void* d_out, int out_size, void* d_ws, size_t ws_size,
                              hipStream_t stream) {
    const float* x       = (const float*)d_in[0];
    const float* g_w     = (const float*)d_in[1];
    const float* g_b     = (const float*)d_in[2];
    const float* theta_w = (const float*)d_in[3];
    const float* theta_b = (const float*)d_in[4];
    const float* phi_w   = (const float*)d_in[5];
    const float* phi_b   = (const float*)d_in[6];
    const float* w_w     = (const float*)d_in[7];
    const float* w_b     = (const float*)d_in[8];
    const float* gamma   = (const float*)d_in[9];
    const float* beta    = (const float*)d_in[10];

    char* ws = (char*)d_ws;
    size_t off = 0;
    auto alloc = [&](size_t bytes) {
        void* p = ws + off;
        off += (bytes + 255) & ~(size_t)255;
        return p;
    };
    short*  wcat  = (short*)alloc((size_t)384 * 256 * 2);
    short*  wwb   = (short*)alloc((size_t)256 * 128 * 2);
    float*  bcat  = (float*)alloc((size_t)384 * 4);
    float*  scale = (float*)alloc(256 * 4);
    float*  shift = (float*)alloc(256 * 4);
    short*  tp    = (short*)alloc((size_t)BN_ * 256 * 2);    // theta|phi 16.78 MB
    short*  gmat  = (short*)alloc((size_t)B_ * I_ * N_ * 2); // 8.39 MB
    short*  wyh   = (short*)alloc((size_t)BN_ * C_ * 2);     // bf16 wy 16.78 MB

    k_prep<<<514, 256, 0, stream>>>(g_w, theta_w, phi_w, g_b, theta_b, phi_b, w_w,
                                    wcat, wwb, bcat);
    k_proj<<<dim3(64, 8), 256, 0, stream>>>(x, wcat, bcat, tp, gmat);
    k_attn_wy<<<256, 512, 0, stream>>>(tp, gmat, wwb, w_b, wyh);  // 8b x 32qt
    k_stats<<<256, 256, 0, stream>>>(wyh, gamma, beta, scale, shift);
    k_out<<<4096, 256, 0, stream>>>(wyh, x, scale, shift, (float*)d_out);
}